// Round 20
// baseline (103.591 us; speedup 1.0000x reference)
//
#include <hip/hip_runtime.h>
#include <math.h>

#define NHEAD 8
#define HEAD_DIM 32
#define IMG_H 32
#define IMG_W 40
#define NPIX (IMG_H*IMG_W)
#define NITER 25          // 5 probes x up to 40 tin-columns = 200 slots / 8 groups
#define FEAT (NHEAD*HEAD_DIM)

// ===== Geometry: LOCKED bit-exact numpy-fp32 emulation (R13 PASSED) =====
// M1 chain (noblas), M2 chain, M3 sgemm-FMA, einsum chain, cc chain; all
// under `#pragma clang fp contract(off)`, FMA only via __builtin_fmaf.

__device__ void np_inv3x3_f32(const float* M, float inv[3][3]) {
#pragma clang fp contract(off)
    float A[3][3]; int piv[3];
    for (int i=0;i<3;i++) { A[i][0]=M[i*3+0]; A[i][1]=M[i*3+1]; A[i][2]=M[i*3+2]; }
    for (int kk=0;kk<3;kk++) {
        int p = kk;
        float colmax = fabsf(A[kk][kk]);
        for (int i=kk+1;i<3;i++) { float vv=fabsf(A[i][kk]); if (vv>colmax){colmax=vv;p=i;} }
        piv[kk] = p;
        if (p!=kk) { for(int j=0;j<3;j++){float tmp=A[kk][j];A[kk][j]=A[p][j];A[p][j]=tmp;} }
        const float rp = 1.0f / A[kk][kk];
        for (int i=kk+1;i<3;i++) A[i][kk] = A[i][kk] * rp;
        for (int i=kk+1;i<3;i++)
            for (int j=kk+1;j<3;j++)
                A[i][j] = A[i][j] - A[i][kk]*A[kk][j];
    }
    for (int col=0; col<3; col++) {
        float b[3] = {0.f,0.f,0.f}; b[col] = 1.0f;
        for (int kk=0;kk<3;kk++) if (piv[kk]!=kk) { float tmp=b[kk]; b[kk]=b[piv[kk]]; b[piv[kk]]=tmp; }
        for (int i=1;i<3;i++)
            for (int kk=0;kk<i;kk++)
                b[i] = b[i] - A[i][kk]*b[kk];
        for (int kk=2;kk>=0;kk--) {
            b[kk] = b[kk] / A[kk][kk];
            for (int i=0;i<kk;i++)
                b[i] = b[i] - A[i][kk]*b[kk];
        }
        inv[0][col]=b[0]; inv[1][col]=b[1]; inv[2][col]=b[2];
    }
}

__device__ void mm3_chain(const float A[3][3], const float B[3][3], float C[3][3]) {
#pragma clang fp contract(off)
    for (int i=0;i<3;i++)
        for (int j=0;j<3;j++) {
            float acc = A[i][0]*B[0][j];
            acc = acc + A[i][1]*B[1][j];
            acc = acc + A[i][2]*B[2][j];
            C[i][j] = acc;
        }
}
__device__ void mm3_fma(const float A[3][3], const float B[3][3], float C[3][3]) {
#pragma clang fp contract(off)
    for (int i=0;i<3;i++)
        for (int j=0;j<3;j++) {
            float acc = A[i][0]*B[0][j];
            acc = __builtin_fmaf(A[i][1], B[1][j], acc);
            acc = __builtin_fmaf(A[i][2], B[2][j], acc);
            C[i][j] = acc;
        }
}
__device__ float einsum_row(const float Fi[3], float x, float y) {
#pragma clang fp contract(off)
    float acc = Fi[0]*x;
    acc = acc + Fi[1]*y;
    acc = acc + Fi[2]*1.0f;
    return acc;
}

__global__ __launch_bounds__(64) void geo_kernel(
    const float* __restrict__ K0, const float* __restrict__ K1,
    const float* __restrict__ R, const float* __restrict__ t,
    float4* __restrict__ geo)
{
#pragma clang fp contract(off)
    const int l = blockIdx.x * 64 + threadIdx.x;   // 20*64 = 1280 exactly
    float i0[3][3], i1[3][3], A[3][3], B[3][3], T1[3][3], T2[3][3], F[3][3], Rm[3][3];
    np_inv3x3_f32(K0, i0);
    np_inv3x3_f32(K1, i1);
    for (int i=0;i<3;i++)
        for (int j=0;j<3;j++) { A[i][j] = i1[j][i]; Rm[i][j] = R[i*3+j]; }
    const float t0=t[0], t1=t[1], t2=t[2];
    B[0][0]=0.f;  B[0][1]=-t2;  B[0][2]=t1;
    B[1][0]=t2;   B[1][1]=0.f;  B[1][2]=-t0;
    B[2][0]=-t1;  B[2][1]=t0;   B[2][2]=0.f;
    mm3_chain(A,B,T1);      // noblas (swapaxes view)
    mm3_chain(T1,Rm,T2);    // T1 @ I
    mm3_fma(T2,i0,F);       // sgemm FMA

    const float xl = (float)(l % IMG_W);
    const float yl = (float)(l / IMG_W);
    const float la = einsum_row(F[0], xl, yl);
    const float lb = einsum_row(F[1], xl, yl);
    const float lc = einsum_row(F[2], xl, yl);
    const bool  mode  = fabsf(lb) > fabsf(la);
    const float denom = mode ? lb : la;
    const float slope = (mode ? -la : -lb) / denom;
    const float icpt  = (-lc) / denom;
    geo[l] = make_float4(slope, icpt, mode ? 1.0f : 0.0f, 0.0f);
}

// ===== R20: analytic candidate enumeration (R19 + defensive clamps) =====
// Candidates for tin-index x are integers strictly in (lo,hi); hi-lo<=4+ulp
// so all lie in {floor(lo)+1 .. floor(lo)+5}: 5 probes/column is a proven
// superset. Validity decided by the bit-identical fp32 comparisons =>
// same candidate SET as R18's scan. Zero LDS, zero barriers. R19 core-
// dumped (cause ambiguous: kernel fault vs infra) — this round clamps yq
// and rows[] into hard bounds (free med3s) to falsify the fault theory.

__global__ __launch_bounds__(512) void one2many_attn(
    const float* __restrict__ q, const float* __restrict__ k, const float* __restrict__ v,
    const float4* __restrict__ geo, float* __restrict__ out)
{
#pragma clang fp contract(off)
    const int l    = blockIdx.x;
    const int tid  = threadIdx.x;
    const int h    = tid >> 6;          // wave = head
    const int lane = tid & 63;
    const int grp  = lane >> 3;         // slot sub-index within 8-group
    const int dj   = (lane & 7) << 2;   // dim offset 0,4,...,28

    const float4 g = geo[l];
    const float slope = g.x;
    const float icpt  = g.y;
    const bool  mode  = (g.z != 0.0f);
    const int tin_n  = mode ? IMG_W : IMG_H;   // columns iterated by tin
    const int chk_n  = mode ? IMG_H : IMG_W;   // probe-value bound

    const float4 q4 = *(const float4*)(q + l*FEAT + h*HEAD_DIM + dj);
    const float* kh = k + h*HEAD_DIM + dj;
    const float* vh = v + h*HEAD_DIM + dj;

    // ---- enumerate + QK: scores into registers ----
    int   rows[NITER];
    float sc[NITER];
    #pragma unroll
    for (int i = 0; i < NITER; i++) {
        const int ci = (i << 3) + grp;       // 0..199 (group-uniform)
        const int xq = ci / 5;               // tin index
        const int pj = ci - xq*5;            // probe 0..4
        const float tin = (float)xq;
        const float mu  = slope * tin;       // exact scan op sequence
        const float cc  = mu + icpt;
        const float hi  = cc + 2.0f;
        const float lo  = cc - 2.0f;
        int yq = (int)floorf(lo) + 1 + pj;   // probe value
        yq = min(max(yq, -1), chk_n);        // clamp: preserves in/out-of-band status
        const float tchk = (float)yq;
        const int xm = mode ? xq : yq;
        const int ym = mode ? yq : xq;
        int m  = ym*IMG_W + xm;
        const bool valid = (xq < tin_n) && (yq >= 0) && (yq < chk_n)
                        && (tchk < hi) && (tchk > lo) && (m != 0);
        m = valid ? m : 0;
        m = min(max(m, 0), NPIX-1);          // hard bound (defensive, free)
        rows[i] = m;
        const float4 kk = *(const float4*)(kh + (size_t)m*FEAT);
        float p = q4.x*kk.x;
        p = __builtin_fmaf(q4.y, kk.y, p);
        p = __builtin_fmaf(q4.z, kk.z, p);
        p = __builtin_fmaf(q4.w, kk.w, p);
        p += __shfl_xor(p, 1);
        p += __shfl_xor(p, 2);
        p += __shfl_xor(p, 4);               // full dot across the 8-group
        sc[i] = valid ? p * 0.17677669529663687f : -INFINITY;
    }

    // ---- softmax in registers; denominator = wave-sum / 8 (exact) ----
    float mx = -INFINITY;
    #pragma unroll
    for (int i = 0; i < NITER; i++) mx = fmaxf(mx, sc[i]);
    #pragma unroll
    for (int o = 32; o; o >>= 1) mx = fmaxf(mx, __shfl_xor(mx, o));
    float losum = 0.f;
    #pragma unroll
    for (int i = 0; i < NITER; i++) {
        const float e = (sc[i] == -INFINITY) ? 0.0f : __expf(sc[i] - mx);
        sc[i] = e;
        losum += e;
    }
    #pragma unroll
    for (int o = 32; o; o >>= 1) losum += __shfl_xor(losum, o);
    const float sum = losum * 0.125f;        // each candidate counted 8x

    // ---- AV: float4 partials per lane, stride-8/16/32 shuffle reduce ----
    float ax = 0.f, ay = 0.f, az = 0.f, aw = 0.f;
    #pragma unroll
    for (int i = 0; i < NITER; i++) {
        const float4 vv = *(const float4*)(vh + (size_t)rows[i]*FEAT);
        ax = __builtin_fmaf(sc[i], vv.x, ax);
        ay = __builtin_fmaf(sc[i], vv.y, ay);
        az = __builtin_fmaf(sc[i], vv.z, az);
        aw = __builtin_fmaf(sc[i], vv.w, aw);
    }
    #pragma unroll
    for (int o = 8; o <= 32; o <<= 1) {
        ax += __shfl_xor(ax, o);
        ay += __shfl_xor(ay, o);
        az += __shfl_xor(az, o);
        aw += __shfl_xor(aw, o);
    }

    if (lane < 8) {
        float4 r;
        if (mx != -INFINITY) { r.x = ax/sum; r.y = ay/sum; r.z = az/sum; r.w = aw/sum; }
        else                 { r.x = r.y = r.z = r.w = 0.0f; }   // all-invalid -> 0 (nan_to_num)
        *(float4*)(out + l*FEAT + h*HEAD_DIM + dj) = r;
    }
}

extern "C" void kernel_launch(void* const* d_in, const int* in_sizes, int n_in,
                              void* d_out, int out_size, void* d_ws, size_t ws_size,
                              hipStream_t stream) {
    const float* q  = (const float*)d_in[0];
    const float* k  = (const float*)d_in[1];
    const float* v  = (const float*)d_in[2];
    const float* K0 = (const float*)d_in[3];
    const float* K1 = (const float*)d_in[4];
    const float* R  = (const float*)d_in[5];
    const float* t  = (const float*)d_in[6];
    float* out = (float*)d_out;
    float4* geo = (float4*)d_ws;        // 1280 x 16 B = 20 KB
    geo_kernel<<<NPIX/64, 64, 0, stream>>>(K0, K1, R, t, geo);
    one2many_attn<<<NPIX, 512, 0, stream>>>(q, k, v, geo, out);
}

// Round 21
// 94.738 us; speedup vs baseline: 1.0934x; 1.0934x over previous
//
#include <hip/hip_runtime.h>
#include <math.h>

#define NHEAD 8
#define HEAD_DIM 32
#define IMG_H 32
#define IMG_W 40
#define NPIX (IMG_H*IMG_W)
#define CMAX 160
#define NITER (CMAX/8)   // 20
#define FEAT (NHEAD*HEAD_DIM)

// ===== Geometry: LOCKED bit-exact numpy-fp32 emulation (R13 PASSED) =====
// M1 chain (noblas), M2 chain, M3 sgemm-FMA, einsum chain, cc chain; all
// under `#pragma clang fp contract(off)`, FMA only via __builtin_fmaf.

__device__ void np_inv3x3_f32(const float* M, float inv[3][3]) {
#pragma clang fp contract(off)
    float A[3][3]; int piv[3];
    for (int i=0;i<3;i++) { A[i][0]=M[i*3+0]; A[i][1]=M[i*3+1]; A[i][2]=M[i*3+2]; }
    for (int kk=0;kk<3;kk++) {
        int p = kk;
        float colmax = fabsf(A[kk][kk]);
        for (int i=kk+1;i<3;i++) { float vv=fabsf(A[i][kk]); if (vv>colmax){colmax=vv;p=i;} }
        piv[kk] = p;
        if (p!=kk) { for(int j=0;j<3;j++){float tmp=A[kk][j];A[kk][j]=A[p][j];A[p][j]=tmp;} }
        const float rp = 1.0f / A[kk][kk];
        for (int i=kk+1;i<3;i++) A[i][kk] = A[i][kk] * rp;
        for (int i=kk+1;i<3;i++)
            for (int j=kk+1;j<3;j++)
                A[i][j] = A[i][j] - A[i][kk]*A[kk][j];
    }
    for (int col=0; col<3; col++) {
        float b[3] = {0.f,0.f,0.f}; b[col] = 1.0f;
        for (int kk=0;kk<3;kk++) if (piv[kk]!=kk) { float tmp=b[kk]; b[kk]=b[piv[kk]]; b[piv[kk]]=tmp; }
        for (int i=1;i<3;i++)
            for (int kk=0;kk<i;kk++)
                b[i] = b[i] - A[i][kk]*b[kk];
        for (int kk=2;kk>=0;kk--) {
            b[kk] = b[kk] / A[kk][kk];
            for (int i=0;i<kk;i++)
                b[i] = b[i] - A[i][kk]*b[kk];
        }
        inv[0][col]=b[0]; inv[1][col]=b[1]; inv[2][col]=b[2];
    }
}

__device__ void mm3_chain(const float A[3][3], const float B[3][3], float C[3][3]) {
#pragma clang fp contract(off)
    for (int i=0;i<3;i++)
        for (int j=0;j<3;j++) {
            float acc = A[i][0]*B[0][j];
            acc = acc + A[i][1]*B[1][j];
            acc = acc + A[i][2]*B[2][j];
            C[i][j] = acc;
        }
}
__device__ void mm3_fma(const float A[3][3], const float B[3][3], float C[3][3]) {
#pragma clang fp contract(off)
    for (int i=0;i<3;i++)
        for (int j=0;j<3;j++) {
            float acc = A[i][0]*B[0][j];
            acc = __builtin_fmaf(A[i][1], B[1][j], acc);
            acc = __builtin_fmaf(A[i][2], B[2][j], acc);
            C[i][j] = acc;
        }
}
__device__ float einsum_row(const float Fi[3], float x, float y) {
#pragma clang fp contract(off)
    float acc = Fi[0]*x;
    acc = acc + Fi[1]*y;
    acc = acc + Fi[2]*1.0f;
    return acc;
}

__global__ __launch_bounds__(64) void geo_kernel(
    const float* __restrict__ K0, const float* __restrict__ K1,
    const float* __restrict__ R, const float* __restrict__ t,
    float4* __restrict__ geo)
{
#pragma clang fp contract(off)
    const int l = blockIdx.x * 64 + threadIdx.x;   // 20*64 = 1280 exactly
    float i0[3][3], i1[3][3], A[3][3], B[3][3], T1[3][3], T2[3][3], F[3][3], Rm[3][3];
    np_inv3x3_f32(K0, i0);
    np_inv3x3_f32(K1, i1);
    for (int i=0;i<3;i++)
        for (int j=0;j<3;j++) { A[i][j] = i1[j][i]; Rm[i][j] = R[i*3+j]; }
    const float t0=t[0], t1=t[1], t2=t[2];
    B[0][0]=0.f;  B[0][1]=-t2;  B[0][2]=t1;
    B[1][0]=t2;   B[1][1]=0.f;  B[1][2]=-t0;
    B[2][0]=-t1;  B[2][1]=t0;   B[2][2]=0.f;
    mm3_chain(A,B,T1);      // noblas (swapaxes view)
    mm3_chain(T1,Rm,T2);    // T1 @ I
    mm3_fma(T2,i0,F);       // sgemm FMA

    const float xl = (float)(l % IMG_W);
    const float yl = (float)(l / IMG_W);
    const float la = einsum_row(F[0], xl, yl);
    const float lb = einsum_row(F[1], xl, yl);
    const float lc = einsum_row(F[2], xl, yl);
    const bool  mode  = fabsf(lb) > fabsf(la);
    const float denom = mode ? lb : la;
    const float slope = (mode ? -la : -lb) / denom;
    const float icpt  = (-lc) / denom;
    geo[l] = make_float4(slope, icpt, mode ? 1.0f : 0.0f, 0.0f);
}

// ===== R21: R18 structure (best: 95.7) + XCD-locality swizzle + direct q4 =====
// R20's analytic enumeration regressed (+25% VMEM slots, enumeration VALU:
// VALUBusy 19->46%, bench 95.7->103.6) -> reverted to the exact-scan R18
// kernel. New: (1) FETCH_SIZE 11MB vs 3.9MB inputs = ~3x cross-XCD L2
// refetch; swizzle l=(bx>>3)+(bx&7)*160 gives each XCD a contiguous
// 160-query strip (working set ~1.3MB << 4MB L2) -> misses become L2 hits.
// (2) s_q staging + its barrier dropped: q4 is a broadcast 2-line load.

__global__ __launch_bounds__(512) void one2many_attn(
    const float* __restrict__ q, const float* __restrict__ k, const float* __restrict__ v,
    const float4* __restrict__ geo, float* __restrict__ out)
{
#pragma clang fp contract(off)
    __shared__ int s_cand[CMAX];
    __shared__ int s_cnt;

    const int bx  = blockIdx.x;
    const int l   = (bx >> 3) + (bx & 7) * 160;   // XCD-contiguous bijection on [0,1280)
    const int tid = threadIdx.x;

    if (tid == 0) s_cnt = 0;

    const float4 g = geo[l];            // broadcast load (L2-resident)
    const float slope = g.x;
    const float icpt  = g.y;
    const bool  mode  = (g.z != 0.0f);
    __syncthreads();   // s_cnt=0 visible

    // ---- candidate collection: identical fp32 band test ----
    for (int m = tid; m < NPIX; m += 512) {
        const float xm = (float)(m % IMG_W), ym = (float)(m / IMG_W);
        const float tin  = mode ? xm : ym;
        const float tchk = mode ? ym : xm;
        const float mu = slope * tin;
        const float cc = mu + icpt;
        const float hi = cc + 2.0f;
        const float lo = cc - 2.0f;
        if ((tchk < hi) && (tchk > lo) && m != 0) {
            int pos = atomicAdd(&s_cnt, 1);
            if (pos < CMAX) s_cand[pos] = m;
        }
    }
    __syncthreads();
    const int nc = min(s_cnt, CMAX);

    const int h    = tid >> 6;          // wave = head
    const int lane = tid & 63;
    const int grp  = lane >> 3;         // candidate sub-index within 8-group
    const int dj   = (lane & 7) << 2;   // dim offset 0,4,...,28

    const float4 q4 = *(const float4*)(q + l*FEAT + h*HEAD_DIM + dj);
    const float* kh = k + h*HEAD_DIM + dj;
    const float* vh = v + h*HEAD_DIM + dj;

    // ---- QK: scores into registers (lane owns candidates grp, grp+8, ...) ----
    int   rows[NITER];
    float sc[NITER];
    #pragma unroll
    for (int i = 0; i < NITER; i++) {
        const int ci = (i << 3) + grp;
        rows[i] = s_cand[(ci < nc) ? ci : 0];
        const float4 kk = *(const float4*)(kh + (size_t)rows[i]*FEAT);
        float p = q4.x*kk.x;
        p = __builtin_fmaf(q4.y, kk.y, p);
        p = __builtin_fmaf(q4.z, kk.z, p);
        p = __builtin_fmaf(q4.w, kk.w, p);
        p += __shfl_xor(p, 1);
        p += __shfl_xor(p, 2);
        p += __shfl_xor(p, 4);              // full dot, identical across 8-group
        sc[i] = (ci < nc) ? p * 0.17677669529663687f : -INFINITY;
    }

    // ---- softmax in registers; denominator = wave-sum / 8 (exact) ----
    float mx = -INFINITY;
    #pragma unroll
    for (int i = 0; i < NITER; i++) mx = fmaxf(mx, sc[i]);
    #pragma unroll
    for (int o = 32; o; o >>= 1) mx = fmaxf(mx, __shfl_xor(mx, o));
    float losum = 0.f;
    #pragma unroll
    for (int i = 0; i < NITER; i++) {
        const float e = __expf(sc[i] - mx);   // expf(-inf)=0 masks invalid slots
        sc[i] = e;
        losum += e;
    }
    #pragma unroll
    for (int o = 32; o; o >>= 1) losum += __shfl_xor(losum, o);
    const float sum = losum * 0.125f;         // each candidate counted 8x

    // ---- AV: float4 partials per lane, stride-8/16/32 shuffle reduce ----
    float ax = 0.f, ay = 0.f, az = 0.f, aw = 0.f;
    #pragma unroll
    for (int i = 0; i < NITER; i++) {
        const float4 vv = *(const float4*)(vh + (size_t)rows[i]*FEAT);
        ax = __builtin_fmaf(sc[i], vv.x, ax);
        ay = __builtin_fmaf(sc[i], vv.y, ay);
        az = __builtin_fmaf(sc[i], vv.z, az);
        aw = __builtin_fmaf(sc[i], vv.w, aw);
    }
    #pragma unroll
    for (int o = 8; o <= 32; o <<= 1) {
        ax += __shfl_xor(ax, o);
        ay += __shfl_xor(ay, o);
        az += __shfl_xor(az, o);
        aw += __shfl_xor(aw, o);
    }

    if (lane < 8) {
        float4 r;
        if (nc > 0) { r.x = ax/sum; r.y = ay/sum; r.z = az/sum; r.w = aw/sum; }
        else        { r.x = r.y = r.z = r.w = 0.0f; }
        *(float4*)(out + l*FEAT + h*HEAD_DIM + dj) = r;
    }
}

extern "C" void kernel_launch(void* const* d_in, const int* in_sizes, int n_in,
                              void* d_out, int out_size, void* d_ws, size_t ws_size,
                              hipStream_t stream) {
    const float* q  = (const float*)d_in[0];
    const float* k  = (const float*)d_in[1];
    const float* v  = (const float*)d_in[2];
    const float* K0 = (const float*)d_in[3];
    const float* K1 = (const float*)d_in[4];
    const float* R  = (const float*)d_in[5];
    const float* t  = (const float*)d_in[6];
    float* out = (float*)d_out;
    float4* geo = (float4*)d_ws;        // 1280 x 16 B = 20 KB
    geo_kernel<<<NPIX/64, 64, 0, stream>>>(K0, K1, R, t, geo);
    one2many_attn<<<NPIX, 512, 0, stream>>>(q, k, v, geo, out);
}